// Round 4
// baseline (28.071 us; speedup 1.0000x reference)
//
#include <hip/hip_runtime.h>

namespace {
constexpr int   kCells      = 512 * 28 * 28;         // 401408
constexpr int   kTPB        = 256;                   // 4 waves
constexpr int   kTileCells  = 256;                   // one cell per thread
constexpr int   kTileF      = kTileCells * 30;       // 7680 floats per tensor
constexpr int   kWaveF      = 64 * 30;               // 1920 floats per wave per tensor
constexpr int   kNBlocks    = kCells / kTileCells;   // 1568 (exact)
constexpr int   kNPart      = kNBlocks * 4;          // one partial per wave
constexpr float kLCoord     = 5.0f;
constexpr float kLNoobj     = 0.5f;
constexpr float kInvS       = 1.0f / 28.0f;
constexpr float kInvN       = 1.0f / 512.0f;
}

__device__ __forceinline__ void async16(const float* g, float* l) {
    __builtin_amdgcn_global_load_lds(
        (const __attribute__((address_space(1))) void*)g,
        (__attribute__((address_space(3))) void*)l,
        16, 0, 0);
}
__device__ __forceinline__ void async4(const float* g, float* l) {
    __builtin_amdgcn_global_load_lds(
        (const __attribute__((address_space(1))) void*)g,
        (__attribute__((address_space(3))) void*)l,
        4, 0, 0);
}

// p, t point at one cell's 30 floats (in LDS).
__device__ __forceinline__ float cell_loss(const float* p, const float* t) {
    const float coo = (t[4] > 0.0f) ? 1.0f : 0.0f;

    const float t_cx = t[0] * kInvS, t_cy = t[1] * kInvS;
    const float t_ltx = t_cx - 0.5f * t[2];
    const float t_lty = t_cy - 0.5f * t[3];
    const float t_rbx = t_cx + 0.5f * t[2];
    const float t_rby = t_cy + 0.5f * t[3];
    const float area2 = (t_rbx - t_ltx) * (t_rby - t_lty);

    float iou0 = 0.0f, iou1 = 0.0f;
    #pragma unroll
    for (int b = 0; b < 2; ++b) {
        const float* pb = p + 5 * b;
        const float p_cx = pb[0] * kInvS, p_cy = pb[1] * kInvS;
        const float p_ltx = p_cx - 0.5f * pb[2];
        const float p_lty = p_cy - 0.5f * pb[3];
        const float p_rbx = p_cx + 0.5f * pb[2];
        const float p_rby = p_cy + 0.5f * pb[3];
        const float ltx = fmaxf(p_ltx, t_ltx);
        const float lty = fmaxf(p_lty, t_lty);
        const float rbx = fminf(p_rbx, t_rbx);
        const float rby = fminf(p_rby, t_rby);
        const float w = fmaxf(rbx - ltx, 0.0f);
        const float h = fmaxf(rby - lty, 0.0f);
        const float inter = w * h;
        const float area1 = (p_rbx - p_ltx) * (p_rby - p_lty);
        const float iou = inter / (area1 + area2 - inter);
        if (b == 0) iou0 = iou; else iou1 = iou;
    }
    // jnp.argmax picks the FIRST max on ties -> idx 1 only if strictly greater.
    const int   max_idx = (iou1 > iou0) ? 1 : 0;
    const float max_iou = fmaxf(iou0, iou1);

    float loc = 0.0f, contain = 0.0f, notresp = 0.0f, nooobj = 0.0f;
    #pragma unroll
    for (int b = 0; b < 2; ++b) {
        const float* pb = p + 5 * b;
        const float* tb = t + 5 * b;
        const float dx = pb[0] - tb[0];
        const float dy = pb[1] - tb[1];
        const float d_xy = dx * dx + dy * dy;
        const float sw = sqrtf(pb[2]) - sqrtf(tb[2]);
        const float sh = sqrtf(pb[3]) - sqrtf(tb[3]);
        const float d_wh = sw * sw + sh * sh;
        const float resp   = (b == max_idx) ? 1.0f : 0.0f;
        const float w_resp = coo * resp;
        const float w_not  = coo * (1.0f - resp);
        loc += w_resp * (d_xy + d_wh);
        const float dc = pb[4] - max_iou;
        contain += w_resp * dc * dc;
        notresp += w_not * pb[4] * pb[4];
        const float dn = pb[4] - tb[4];
        nooobj += (1.0f - coo) * dn * dn;
    }

    float cls = 0.0f;
    #pragma unroll
    for (int j = 10; j < 30; ++j) {
        const float d = p[j] - t[j];
        cls += d * d;
    }
    cls *= coo;

    return kLCoord * loc + contain + kLNoobj * (notresp + nooobj) + cls;
}

// 256-thread blocks, but each wave is self-contained: it stages its own
// 64 cells and waits only on its own vmcnt. NO __syncthreads anywhere.
template <bool USE_WS>
__global__ __launch_bounds__(kTPB) void yolo_loss_kernel(
        const float* __restrict__ pred,
        const float* __restrict__ targ,
        float* __restrict__ dst) {
    __shared__ float lp[kTileF];
    __shared__ float lt[kTileF];

    const int tid  = threadIdx.x;
    const int lane = tid & 63;
    const int wid  = tid >> 6;

    // This wave's 1920-float region of each tensor.
    const float* gp = pred + (size_t)blockIdx.x * kTileF + wid * kWaveF;
    const float* gt = targ + (size_t)blockIdx.x * kTileF + wid * kWaveF;
    float* wlp = &lp[wid * kWaveF];
    float* wlt = &lt[wid * kWaveF];

    // Exact coverage of 1920 floats: 7 chunks of 64x16B (1792 floats)
    // + 2 chunks of 64x4B (128 floats). No over-fetch, no overlap.
    #pragma unroll
    for (int c = 0; c < 7; ++c) {
        const int f = c * 256 + lane * 4;
        async16(gp + f, wlp + c * 256);
        async16(gt + f, wlt + c * 256);
    }
    #pragma unroll
    for (int c = 0; c < 2; ++c) {
        const int f = 1792 + c * 64 + lane;
        async4(gp + f, wlp + 1792 + c * 64);
        async4(gt + f, wlt + 1792 + c * 64);
    }
    asm volatile("s_waitcnt vmcnt(0)" ::: "memory");

    float local = cell_loss(&lp[tid * 30], &lt[tid * 30]);

    #pragma unroll
    for (int off = 32; off > 0; off >>= 1)
        local += __shfl_down(local, off, 64);

    if (lane == 0) {
        if (USE_WS) dst[blockIdx.x * 4 + wid] = local;
        else        atomicAdd(dst, local * kInvN);
    }
}

__global__ __launch_bounds__(256) void reduce_kernel(
        const float* __restrict__ part, float* __restrict__ out) {
    __shared__ float wsum[4];
    float s = 0.0f;
    for (int i = threadIdx.x; i < kNPart; i += 256) s += part[i];
    #pragma unroll
    for (int off = 32; off > 0; off >>= 1)
        s += __shfl_down(s, off, 64);
    const int lane = threadIdx.x & 63;
    const int wid  = threadIdx.x >> 6;
    if (lane == 0) wsum[wid] = s;
    __syncthreads();
    if (threadIdx.x == 0)
        out[0] = (wsum[0] + wsum[1] + wsum[2] + wsum[3]) * kInvN;
}

__global__ void zero_out_kernel(float* __restrict__ out) {
    if (threadIdx.x == 0) out[0] = 0.0f;
}

extern "C" void kernel_launch(void* const* d_in, const int* in_sizes, int n_in,
                              void* d_out, int out_size, void* d_ws, size_t ws_size,
                              hipStream_t stream) {
    const float* pred = (const float*)d_in[0];
    const float* targ = (const float*)d_in[1];
    float* out = (float*)d_out;

    if (ws_size >= (size_t)kNPart * sizeof(float)) {
        float* part = (float*)d_ws;
        yolo_loss_kernel<true><<<kNBlocks, kTPB, 0, stream>>>(pred, targ, part);
        reduce_kernel<<<1, 256, 0, stream>>>(part, out);
    } else {
        zero_out_kernel<<<1, 64, 0, stream>>>(out);
        yolo_loss_kernel<false><<<kNBlocks, kTPB, 0, stream>>>(pred, targ, out);
    }
}

// Round 5
// 24.776 us; speedup vs baseline: 1.1330x; 1.1330x over previous
//
#include <hip/hip_runtime.h>

namespace {
constexpr int   kCells     = 512 * 28 * 28;            // 401408
constexpr int   kTileCells = 64;                       // one cell per lane per tile
constexpr int   kNTiles    = kCells / kTileCells;      // 6272 (exact)
constexpr int   kWaveF     = kTileCells * 30;          // 1920 floats per tensor per tile
constexpr int   kNWaves    = 1280;                     // 5 blocks/CU x 256 CUs, 1 wave each
constexpr float kLCoord    = 5.0f;
constexpr float kLNoobj    = 0.5f;
constexpr float kInvS      = 1.0f / 28.0f;
constexpr float kInvN      = 1.0f / 512.0f;
}

__device__ __forceinline__ void async16(const float* g, float* l) {
    __builtin_amdgcn_global_load_lds(
        (const __attribute__((address_space(1))) void*)g,
        (__attribute__((address_space(3))) void*)l,
        16, 0, 0);
}
__device__ __forceinline__ void async4(const float* g, float* l) {
    __builtin_amdgcn_global_load_lds(
        (const __attribute__((address_space(1))) void*)g,
        (__attribute__((address_space(3))) void*)l,
        4, 0, 0);
}

// p, t point at one cell's 30 floats (in LDS).
__device__ __forceinline__ float cell_loss(const float* p, const float* t) {
    const float coo = (t[4] > 0.0f) ? 1.0f : 0.0f;

    const float t_cx = t[0] * kInvS, t_cy = t[1] * kInvS;
    const float t_ltx = t_cx - 0.5f * t[2];
    const float t_lty = t_cy - 0.5f * t[3];
    const float t_rbx = t_cx + 0.5f * t[2];
    const float t_rby = t_cy + 0.5f * t[3];
    const float area2 = (t_rbx - t_ltx) * (t_rby - t_lty);

    float iou0 = 0.0f, iou1 = 0.0f;
    #pragma unroll
    for (int b = 0; b < 2; ++b) {
        const float* pb = p + 5 * b;
        const float p_cx = pb[0] * kInvS, p_cy = pb[1] * kInvS;
        const float p_ltx = p_cx - 0.5f * pb[2];
        const float p_lty = p_cy - 0.5f * pb[3];
        const float p_rbx = p_cx + 0.5f * pb[2];
        const float p_rby = p_cy + 0.5f * pb[3];
        const float ltx = fmaxf(p_ltx, t_ltx);
        const float lty = fmaxf(p_lty, t_lty);
        const float rbx = fminf(p_rbx, t_rbx);
        const float rby = fminf(p_rby, t_rby);
        const float w = fmaxf(rbx - ltx, 0.0f);
        const float h = fmaxf(rby - lty, 0.0f);
        const float inter = w * h;
        const float area1 = (p_rbx - p_ltx) * (p_rby - p_lty);
        const float iou = inter / (area1 + area2 - inter);
        if (b == 0) iou0 = iou; else iou1 = iou;
    }
    // jnp.argmax picks the FIRST max on ties -> idx 1 only if strictly greater.
    const int   max_idx = (iou1 > iou0) ? 1 : 0;
    const float max_iou = fmaxf(iou0, iou1);

    float loc = 0.0f, contain = 0.0f, notresp = 0.0f, nooobj = 0.0f;
    #pragma unroll
    for (int b = 0; b < 2; ++b) {
        const float* pb = p + 5 * b;
        const float* tb = t + 5 * b;
        const float dx = pb[0] - tb[0];
        const float dy = pb[1] - tb[1];
        const float d_xy = dx * dx + dy * dy;
        const float sw = sqrtf(pb[2]) - sqrtf(tb[2]);
        const float sh = sqrtf(pb[3]) - sqrtf(tb[3]);
        const float d_wh = sw * sw + sh * sh;
        const float resp   = (b == max_idx) ? 1.0f : 0.0f;
        const float w_resp = coo * resp;
        const float w_not  = coo * (1.0f - resp);
        loc += w_resp * (d_xy + d_wh);
        const float dc = pb[4] - max_iou;
        contain += w_resp * dc * dc;
        notresp += w_not * pb[4] * pb[4];
        const float dn = pb[4] - tb[4];
        nooobj += (1.0f - coo) * dn * dn;
    }

    float cls = 0.0f;
    #pragma unroll
    for (int j = 10; j < 30; ++j) {
        const float d = p[j] - t[j];
        cls += d * d;
    }
    cls *= coo;

    return kLCoord * loc + contain + kLNoobj * (notresp + nooobj) + cls;
}

// Persistent single-wave blocks. Each wave double-buffers its own tiles and
// keeps 18 loads (~15 KiB) in flight across compute via counted vmcnt.
// No __syncthreads anywhere; vmcnt/lgkmcnt are per-wave.
template <bool USE_WS>
__global__ __launch_bounds__(64) void yolo_loss_kernel(
        const float* __restrict__ pred,
        const float* __restrict__ targ,
        float* __restrict__ dst) {
    __shared__ float lp[2][kWaveF];
    __shared__ float lt[2][kWaveF];

    const int lane = threadIdx.x;          // 0..63
    const int w    = blockIdx.x;           // wave id, 0..kNWaves-1

    // Tiles for this wave: w, w+kNWaves, w+2*kNWaves, ...
    const int T = 1 + (kNTiles - 1 - w) / kNWaves;   // 4 or 5

    // Issue exactly 18 loads per tile: per tensor 7x(64 lanes x 16B) + 2x(64 x 4B).
    auto stage = [&](int tile, int buf) {
        const float* gp = pred + (size_t)tile * kWaveF;
        const float* gt = targ + (size_t)tile * kWaveF;
        #pragma unroll
        for (int c = 0; c < 7; ++c) {
            const int f = c * 256 + lane * 4;
            async16(gp + f, &lp[buf][c * 256]);
            async16(gt + f, &lt[buf][c * 256]);
        }
        #pragma unroll
        for (int c = 0; c < 2; ++c) {
            const int f = 1792 + c * 64 + lane;
            async4(gp + f, &lp[buf][1792 + c * 64]);
            async4(gt + f, &lt[buf][1792 + c * 64]);
        }
    };

    stage(w, 0);
    if (T > 1) stage(w + kNWaves, 1);

    float acc = 0.0f;
    for (int i = 0; i < T; ++i) {
        const int cur = i & 1;
        if (i + 1 < T) {
            // Oldest 18 (tile i) retired; tile i+1's 18 stay in flight.
            asm volatile("s_waitcnt vmcnt(18)" ::: "memory");
        } else {
            asm volatile("s_waitcnt vmcnt(0)" ::: "memory");
        }
        acc += cell_loss(&lp[cur][lane * 30], &lt[cur][lane * 30]);
        if (i + 2 < T) {
            // All ds_reads of buf[cur] must complete before DMA overwrites it.
            asm volatile("s_waitcnt lgkmcnt(0)" ::: "memory");
            stage(w + (i + 2) * kNWaves, cur);
        }
    }

    #pragma unroll
    for (int off = 32; off > 0; off >>= 1)
        acc += __shfl_down(acc, off, 64);

    if (lane == 0) {
        if (USE_WS) dst[w] = acc;
        else        atomicAdd(dst, acc * kInvN);
    }
}

__global__ __launch_bounds__(256) void reduce_kernel(
        const float* __restrict__ part, float* __restrict__ out) {
    __shared__ float wsum[4];
    float s = 0.0f;
    for (int i = threadIdx.x; i < kNWaves; i += 256) s += part[i];
    #pragma unroll
    for (int off = 32; off > 0; off >>= 1)
        s += __shfl_down(s, off, 64);
    const int lane = threadIdx.x & 63;
    const int wid  = threadIdx.x >> 6;
    if (lane == 0) wsum[wid] = s;
    __syncthreads();
    if (threadIdx.x == 0)
        out[0] = (wsum[0] + wsum[1] + wsum[2] + wsum[3]) * kInvN;
}

__global__ void zero_out_kernel(float* __restrict__ out) {
    if (threadIdx.x == 0) out[0] = 0.0f;
}

extern "C" void kernel_launch(void* const* d_in, const int* in_sizes, int n_in,
                              void* d_out, int out_size, void* d_ws, size_t ws_size,
                              hipStream_t stream) {
    const float* pred = (const float*)d_in[0];
    const float* targ = (const float*)d_in[1];
    float* out = (float*)d_out;

    if (ws_size >= (size_t)kNWaves * sizeof(float)) {
        float* part = (float*)d_ws;
        yolo_loss_kernel<true><<<kNWaves, 64, 0, stream>>>(pred, targ, part);
        reduce_kernel<<<1, 256, 0, stream>>>(part, out);
    } else {
        zero_out_kernel<<<1, 64, 0, stream>>>(out);
        yolo_loss_kernel<false><<<kNWaves, 64, 0, stream>>>(pred, targ, out);
    }
}

// Round 6
// 23.425 us; speedup vs baseline: 1.1983x; 1.0577x over previous
//
#include <hip/hip_runtime.h>

namespace {
constexpr int   kCells     = 512 * 28 * 28;          // 401408
constexpr int   kHalfCells = 128;                    // cells per half-tile
constexpr int   kHalfF     = kHalfCells * 30;        // 3840 floats = 15 x 256 (clean 16B DMA)
constexpr int   kNHalves   = kCells / kHalfCells;    // 3136 (exact)
constexpr int   kNBlk      = 512;                    // 2 blocks/CU
constexpr int   kBaseH     = kNHalves / kNBlk;       // 6
constexpr int   kExtra     = kNHalves % kNBlk;       // 64 blocks get 7
constexpr float kLCoord    = 5.0f;
constexpr float kLNoobj    = 0.5f;
constexpr float kInvS      = 1.0f / 28.0f;
constexpr float kInvN      = 1.0f / 512.0f;
}

__device__ __forceinline__ void async16(const float* g, float* l) {
    __builtin_amdgcn_global_load_lds(
        (const __attribute__((address_space(1))) void*)g,
        (__attribute__((address_space(3))) void*)l,
        16, 0, 0);
}
__device__ __forceinline__ void wait_vm15() { asm volatile("s_waitcnt vmcnt(15)" ::: "memory"); }
__device__ __forceinline__ void wait_vm0()  { asm volatile("s_waitcnt vmcnt(0)"  ::: "memory"); }

// p, t point at one cell's 30 floats (in LDS).
__device__ __forceinline__ float cell_loss(const float* p, const float* t) {
    const float coo = (t[4] > 0.0f) ? 1.0f : 0.0f;

    const float t_cx = t[0] * kInvS, t_cy = t[1] * kInvS;
    const float t_ltx = t_cx - 0.5f * t[2];
    const float t_lty = t_cy - 0.5f * t[3];
    const float t_rbx = t_cx + 0.5f * t[2];
    const float t_rby = t_cy + 0.5f * t[3];
    const float area2 = (t_rbx - t_ltx) * (t_rby - t_lty);

    float iou0 = 0.0f, iou1 = 0.0f;
    #pragma unroll
    for (int b = 0; b < 2; ++b) {
        const float* pb = p + 5 * b;
        const float p_cx = pb[0] * kInvS, p_cy = pb[1] * kInvS;
        const float p_ltx = p_cx - 0.5f * pb[2];
        const float p_lty = p_cy - 0.5f * pb[3];
        const float p_rbx = p_cx + 0.5f * pb[2];
        const float p_rby = p_cy + 0.5f * pb[3];
        const float ltx = fmaxf(p_ltx, t_ltx);
        const float lty = fmaxf(p_lty, t_lty);
        const float rbx = fminf(p_rbx, t_rbx);
        const float rby = fminf(p_rby, t_rby);
        const float w = fmaxf(rbx - ltx, 0.0f);
        const float h = fmaxf(rby - lty, 0.0f);
        const float inter = w * h;
        const float area1 = (p_rbx - p_ltx) * (p_rby - p_lty);
        const float iou = inter / (area1 + area2 - inter);
        if (b == 0) iou0 = iou; else iou1 = iou;
    }
    // jnp.argmax picks the FIRST max on ties -> idx 1 only if strictly greater.
    const int   max_idx = (iou1 > iou0) ? 1 : 0;
    const float max_iou = fmaxf(iou0, iou1);

    float loc = 0.0f, contain = 0.0f, notresp = 0.0f, nooobj = 0.0f;
    #pragma unroll
    for (int b = 0; b < 2; ++b) {
        const float* pb = p + 5 * b;
        const float* tb = t + 5 * b;
        const float dx = pb[0] - tb[0];
        const float dy = pb[1] - tb[1];
        const float d_xy = dx * dx + dy * dy;
        const float sw = sqrtf(pb[2]) - sqrtf(tb[2]);
        const float sh = sqrtf(pb[3]) - sqrtf(tb[3]);
        const float d_wh = sw * sw + sh * sh;
        const float resp   = (b == max_idx) ? 1.0f : 0.0f;
        const float w_resp = coo * resp;
        const float w_not  = coo * (1.0f - resp);
        loc += w_resp * (d_xy + d_wh);
        const float dc = pb[4] - max_iou;
        contain += w_resp * dc * dc;
        notresp += w_not * pb[4] * pb[4];
        const float dn = pb[4] - tb[4];
        nooobj += (1.0f - coo) * dn * dn;
    }

    float cls = 0.0f;
    #pragma unroll
    for (int j = 10; j < 30; ++j) {
        const float d = p[j] - t[j];
        cls += d * d;
    }
    cls *= coo;

    return kLCoord * loc + contain + kLNoobj * (notresp + nooobj) + cls;
}

// Persistent 2-wave blocks, contiguous half-tile ranges, double-buffered LDS,
// counted vmcnt (never drains to 0 mid-loop), raw s_barrier.
// Wave 0 stages pred, wave 1 stages targ -> 2 long sequential HBM streams/block.
template <bool USE_WS>
__global__ __launch_bounds__(128) void yolo_loss_kernel(
        const float* __restrict__ pred,
        const float* __restrict__ targ,
        float* __restrict__ dst) {
    __shared__ float lp[2][kHalfF];
    __shared__ float lt[2][kHalfF];
    __shared__ float wsum[2];

    const int tid  = threadIdx.x;
    const int lane = tid & 63;
    const int wid  = tid >> 6;          // 0: stages pred, 1: stages targ
    const int b    = blockIdx.x;

    // Blocks 0..kExtra-1 take kBaseH+1 halves (one heavy block per CU max).
    const int h0 = b * kBaseH + min(b, kExtra);
    const int H  = kBaseH + (b < kExtra ? 1 : 0);

    const float* gsrc = (wid == 0) ? pred : targ;

    auto stage = [&](int h, int buf) {
        const float* g = gsrc + (size_t)h * kHalfF;
        float* l = (wid == 0) ? &lp[buf][0] : &lt[buf][0];
        #pragma unroll
        for (int c = 0; c < 15; ++c) {
            const int f = c * 256 + lane * 4;
            async16(g + f, l + c * 256);
        }
    };

    stage(h0, 0);
    if (H > 1) stage(h0 + 1, 1);

    float acc = 0.0f;
    for (int i = 0; i < H; ++i) {
        const int buf = i & 1;
        // Wait for half i's 15 loads; half i+1's 15 stay in flight.
        if (i + 1 < H) wait_vm15(); else wait_vm0();
        __builtin_amdgcn_s_barrier();            // all of half i is in LDS
        acc += cell_loss(&lp[buf][tid * 30], &lt[buf][tid * 30]);
        if (i + 2 < H) {
            __builtin_amdgcn_s_barrier();        // all waves done reading buf
            stage(h0 + i + 2, buf);
        }
    }

    #pragma unroll
    for (int off = 32; off > 0; off >>= 1)
        acc += __shfl_down(acc, off, 64);
    if (lane == 0) wsum[wid] = acc;
    __syncthreads();
    if (tid == 0) {
        const float s = wsum[0] + wsum[1];
        if (USE_WS) dst[b] = s;
        else        atomicAdd(dst, s * kInvN);
    }
}

__global__ __launch_bounds__(256) void reduce_kernel(
        const float* __restrict__ part, float* __restrict__ out) {
    __shared__ float wsum[4];
    float s = 0.0f;
    for (int i = threadIdx.x; i < kNBlk; i += 256) s += part[i];
    #pragma unroll
    for (int off = 32; off > 0; off >>= 1)
        s += __shfl_down(s, off, 64);
    const int lane = threadIdx.x & 63;
    const int wid  = threadIdx.x >> 6;
    if (lane == 0) wsum[wid] = s;
    __syncthreads();
    if (threadIdx.x == 0)
        out[0] = (wsum[0] + wsum[1] + wsum[2] + wsum[3]) * kInvN;
}

__global__ void zero_out_kernel(float* __restrict__ out) {
    if (threadIdx.x == 0) out[0] = 0.0f;
}

extern "C" void kernel_launch(void* const* d_in, const int* in_sizes, int n_in,
                              void* d_out, int out_size, void* d_ws, size_t ws_size,
                              hipStream_t stream) {
    const float* pred = (const float*)d_in[0];
    const float* targ = (const float*)d_in[1];
    float* out = (float*)d_out;

    if (ws_size >= (size_t)kNBlk * sizeof(float)) {
        float* part = (float*)d_ws;
        yolo_loss_kernel<true><<<kNBlk, 128, 0, stream>>>(pred, targ, part);
        reduce_kernel<<<1, 256, 0, stream>>>(part, out);
    } else {
        zero_out_kernel<<<1, 64, 0, stream>>>(out);
        yolo_loss_kernel<false><<<kNBlk, 128, 0, stream>>>(pred, targ, out);
    }
}